// Round 1
// baseline (44.338 us; speedup 1.0000x reference)
//
#include <hip/hip_runtime.h>

#define BB 256
#define PP 64
#define LL 16
#define DD 64
#define IMGF 512
#define META_N 50000

__device__ __forceinline__ float wred_sum(float v) {
#pragma unroll
    for (int off = 32; off > 0; off >>= 1) v += __shfl_xor(v, off, 64);
    return v;
}

// Kernel 0: reciprocal L2 norm of every meta_embed row (one wave per row)
__global__ void k_meta_norm(const float* __restrict__ meta, float* __restrict__ rnorm) {
    int wave = threadIdx.x >> 6;
    int lane = threadIdx.x & 63;
    int row = blockIdx.x * 4 + wave;
    if (row >= META_N) return;
    float x = meta[row * DD + lane];
    float s = wred_sum(x * x);
    float rn = 1.0f / fmaxf(sqrtf(s), 1e-12f);
    if (lane == 0) rnorm[row] = rn;
}

// Kernel 1: qry_fea / res_fea.  grid = 2*B blocks of 64; lane = output dim d.
__global__ void k_img(const int* __restrict__ qry_id, const int* __restrict__ res_id,
                      const float* __restrict__ img, const float* __restrict__ Ww,
                      const float* __restrict__ Wb,
                      float* __restrict__ qf, float* __restrict__ rf) {
    __shared__ float4 fea[IMGF / 4];
    int bi = blockIdx.x;
    int b = bi & (BB - 1);
    int which = bi >> 8;
    int lane = threadIdx.x;
    int id = which ? res_id[b] : qry_id[b];
    const float4* src = (const float4*)(img + (long long)id * IMGF);
#pragma unroll
    for (int i = 0; i < IMGF / 4 / 64; ++i) fea[lane + i * 64] = src[lane + i * 64];
    __syncthreads();
    const float4* wrow = (const float4*)(Ww + lane * IMGF);
    float acc = Wb[lane];
#pragma unroll 4
    for (int k = 0; k < IMGF / 4; ++k) {
        float4 a = fea[k], w = wrow[k];
        acc += a.x * w.x + a.y * w.y + a.z * w.z + a.w * w.w;
    }
    float n = wred_sum(acc * acc);
    float v = acc / fmaxf(sqrtf(n), 1e-12f);
    (which ? rf : qf)[b * DD + lane] = v;
}

// Kernel 2: per-(b,p) path processing. grid = B*P blocks of 64; lane = d.
__global__ void k_path(const int* __restrict__ path, const int* __restrict__ mask,
                       const float* __restrict__ meta, const float* __restrict__ rnorm,
                       const float* __restrict__ qf, const float* __restrict__ rf,
                       const float* __restrict__ hw, const float* __restrict__ hb,
                       float* __restrict__ path_res, float* __restrict__ weight) {
    int bp = blockIdx.x;
    int b = bp >> 6;           // / PP
    int p = bp & (PP - 1);
    int lane = threadIdx.x;
    const int* pp = path + (b * PP + p) * LL;
    const int* mm = mask + (b * PP + p) * LL;
    float pm[8];
#pragma unroll
    for (int j = 0; j < 8; ++j) pm[j] = 0.0f;
#pragma unroll
    for (int l = 0; l < LL; ++l) {
        int idx = pp[l];
        float x = meta[idx * DD + lane] * rnorm[idx] * (float)mm[l];
        pm[l >> 1] += x;
    }
    float a2 = 0.f, a3 = 0.f, a4 = 0.f;
#pragma unroll
    for (int k = 0; k < 7; ++k) a2 += pm[k] * pm[k + 1];
#pragma unroll
    for (int k = 0; k < 6; ++k) a3 += pm[k] * pm[k + 1] * pm[k + 2];
#pragma unroll
    for (int k = 0; k < 5; ++k) a4 += pm[k] * pm[k + 1] * pm[k + 2] * pm[k + 3];
    a2 *= (1.0f / 7.0f);
    a3 *= (1.0f / 6.0f);
    a4 *= (1.0f / 5.0f);
    float n2 = wred_sum(a2 * a2);
    float n3 = wred_sum(a3 * a3);
    float n4 = wred_sum(a4 * a4);
    float r1 = a2 / fmaxf(sqrtf(n2), 1e-12f);
    float r2 = a3 / fmaxf(sqrtf(n3), 1e-12f);
    float r3 = a4 / fmaxf(sqrtf(n4), 1e-12f);
    float pr = (r1 + r2 + r3) * (1.0f / 3.0f);
    path_res[(b * PP + p) * DD + lane] = pr;
    float qm = qf[b * DD + lane], rs = rf[b * DD + lane];
    // fusion = [-(qry-res)*path_res , qry*res] dot h_att_w
    float term = -(qm - rs) * pr * hw[lane] + (qm * rs) * hw[DD + lane];
    float wsum = wred_sum(term);
    if (lane == 0) weight[b * PP + p] = wsum + hb[0];
}

// Kernel 3: per-b softmax over P, pooled, final scores. grid = B blocks of 64.
__global__ void k_final(const float* __restrict__ weight, const float* __restrict__ path_res,
                        const float* __restrict__ qf, const float* __restrict__ rf,
                        const float* __restrict__ p1w, const float* __restrict__ p1b,
                        const float* __restrict__ p2w, const float* __restrict__ p2b,
                        float* __restrict__ out) {
    __shared__ float wsh[PP];
    int b = blockIdx.x;
    int lane = threadIdx.x;
    float wt = weight[b * PP + lane] * 5.0f;   // /0.2
    float mx = wt;
#pragma unroll
    for (int off = 32; off > 0; off >>= 1) mx = fmaxf(mx, __shfl_xor(mx, off, 64));
    float e = expf(wt - mx);
    float s = wred_sum(e);
    wsh[lane] = e / s;
    __syncthreads();
    float pooled = 0.0f;
    const float* prb = path_res + b * PP * DD;
#pragma unroll 8
    for (int p = 0; p < PP; ++p) pooled += prb[p * DD + lane] * wsh[p];
    float qm = qf[b * DD + lane], rs = rf[b * DD + lane];
    float s1 = wred_sum(qm * rs * p1w[lane]);
    float s2 = wred_sum((rs - qm) * pooled * p2w[lane]);
    if (lane == 0) out[b] = (s1 + p1b[0]) + 5.0f * (s2 + p2b[0]);
}

extern "C" void kernel_launch(void* const* d_in, const int* in_sizes, int n_in,
                              void* d_out, int out_size, void* d_ws, size_t ws_size,
                              hipStream_t stream) {
    const int*   qry_id = (const int*)d_in[0];
    const int*   res_id = (const int*)d_in[1];
    const int*   path   = (const int*)d_in[2];
    const int*   mask   = (const int*)d_in[3];
    const float* img    = (const float*)d_in[4];
    const float* Ww     = (const float*)d_in[5];
    const float* Wb     = (const float*)d_in[6];
    const float* meta   = (const float*)d_in[7];
    const float* hw     = (const float*)d_in[8];
    const float* hb     = (const float*)d_in[9];
    const float* p1w    = (const float*)d_in[10];
    const float* p1b    = (const float*)d_in[11];
    const float* p2w    = (const float*)d_in[12];
    const float* p2b    = (const float*)d_in[13];

    float* ws       = (float*)d_ws;
    float* rnorm    = ws;                       // 50000 (pad 50048)
    float* qf       = ws + 50048;               // B*D
    float* rf       = qf + BB * DD;             // B*D
    float* path_res = rf + BB * DD;             // B*P*D
    float* weight   = path_res + BB * PP * DD;  // B*P
    float* out      = (float*)d_out;

    hipLaunchKernelGGL(k_meta_norm, dim3((META_N + 3) / 4), dim3(256), 0, stream,
                       meta, rnorm);
    hipLaunchKernelGGL(k_img, dim3(2 * BB), dim3(64), 0, stream,
                       qry_id, res_id, img, Ww, Wb, qf, rf);
    hipLaunchKernelGGL(k_path, dim3(BB * PP), dim3(64), 0, stream,
                       path, mask, meta, rnorm, qf, rf, hw, hb, path_res, weight);
    hipLaunchKernelGGL(k_final, dim3(BB), dim3(64), 0, stream,
                       weight, path_res, qf, rf, p1w, p1b, p2w, p2b, out);
}

// Round 2
// 31.699 us; speedup vs baseline: 1.3987x; 1.3987x over previous
//
#include <hip/hip_runtime.h>

#define BB 256
#define PP 64
#define LL 16
#define DD 64
#define IMGF 512
#define META_N 50000

__device__ __forceinline__ float wred_sum(float v) {
#pragma unroll
    for (int off = 32; off > 0; off >>= 1) v += __shfl_xor(v, off, 64);
    return v;
}

// Kernel 0: reciprocal L2 norm of every meta_embed row (one wave per row)
__global__ void k_meta_norm(const float* __restrict__ meta, float* __restrict__ rnorm) {
    int wave = threadIdx.x >> 6;
    int lane = threadIdx.x & 63;
    int row = blockIdx.x * 4 + wave;
    if (row >= META_N) return;
    float x = meta[row * DD + lane];
    float s = wred_sum(x * x);
    if (lane == 0) rnorm[row] = 1.0f / fmaxf(sqrtf(s), 1e-12f);
}

// Fused: img GEMV + l2norm, path processing, softmax pooling, final scores.
// One block of 1024 threads (16 waves) per batch element b.
__launch_bounds__(1024, 1)
__global__ void k_fused(const int* __restrict__ qry_id, const int* __restrict__ res_id,
                        const int* __restrict__ path, const int* __restrict__ mask,
                        const float* __restrict__ img, const float* __restrict__ Ww,
                        const float* __restrict__ Wb,
                        const float* __restrict__ meta, const float* __restrict__ rnorm,
                        const float* __restrict__ hw, const float* __restrict__ hb,
                        const float* __restrict__ p1w, const float* __restrict__ p1b,
                        const float* __restrict__ p2w, const float* __restrict__ p2b,
                        float* __restrict__ out) {
    __shared__ float fq[IMGF], fr[IMGF];         // staged image feature rows
    __shared__ float pq[16][DD], prt[16][DD];    // GEMV partials
    __shared__ float qf[DD], rf[DD];             // normalized features
    __shared__ float pr_sh[PP][DD];              // path_res
    __shared__ float weight_sh[PP];
    __shared__ float wsh[PP];

    int b = blockIdx.x;
    int tid = threadIdx.x;
    int lane = tid & 63;
    int wv = tid >> 6;   // 0..15

    // ---- stage the two gathered image-feature rows (coalesced) ----
    {
        int qid = qry_id[b], rid = res_id[b];
        if (tid < IMGF) fq[tid] = img[(long long)qid * IMGF + tid];
        else            fr[tid - IMGF] = img[(long long)rid * IMGF + (tid - IMGF)];
    }
    __syncthreads();

    // ---- GEMV: output d = lane, k-slice = wv (32 k each) ----
    {
        float aq = 0.f, ar = 0.f;
        const float* wrow = Ww + lane * IMGF + wv * 32;
        const float* q0 = fq + wv * 32;
        const float* r0 = fr + wv * 32;
#pragma unroll
        for (int k = 0; k < 32; k += 4) {
            float4 w4 = *(const float4*)(wrow + k);
            aq += w4.x * q0[k] + w4.y * q0[k + 1] + w4.z * q0[k + 2] + w4.w * q0[k + 3];
            ar += w4.x * r0[k] + w4.y * r0[k + 1] + w4.z * r0[k + 2] + w4.w * r0[k + 3];
        }
        pq[wv][lane] = aq;
        prt[wv][lane] = ar;
    }
    __syncthreads();
    if (wv < 2) {
        float acc = Wb[lane];
#pragma unroll
        for (int s = 0; s < 16; ++s) acc += (wv ? prt[s][lane] : pq[s][lane]);
        float n = wred_sum(acc * acc);
        float v = acc / fmaxf(sqrtf(n), 1e-12f);
        (wv ? rf : qf)[lane] = v;
    }
    __syncthreads();

    // ---- path phase: each wave handles 4 p values ----
    float qv = qf[lane], rv = rf[lane];
    float h0 = hw[lane], h1 = hw[DD + lane];
#pragma unroll
    for (int i = 0; i < 4; ++i) {
        int p = wv * 4 + i;
        const int* pp = path + (b * PP + p) * LL;
        const int* mm = mask + (b * PP + p) * LL;
        float pm[8];
#pragma unroll
        for (int j = 0; j < 8; ++j) pm[j] = 0.f;
#pragma unroll
        for (int l = 0; l < LL; ++l) {
            int idx = pp[l];
            float x = meta[idx * DD + lane] * (rnorm[idx] * (float)mm[l]);
            pm[l >> 1] += x;
        }
        float a2 = 0.f, a3 = 0.f, a4 = 0.f;
#pragma unroll
        for (int k = 0; k < 7; ++k) a2 += pm[k] * pm[k + 1];
#pragma unroll
        for (int k = 0; k < 6; ++k) a3 += pm[k] * pm[k + 1] * pm[k + 2];
#pragma unroll
        for (int k = 0; k < 5; ++k) a4 += pm[k] * pm[k + 1] * pm[k + 2] * pm[k + 3];
        a2 *= (1.0f / 7.0f);
        a3 *= (1.0f / 6.0f);
        a4 *= (1.0f / 5.0f);
        float n2 = wred_sum(a2 * a2);
        float n3 = wred_sum(a3 * a3);
        float n4 = wred_sum(a4 * a4);
        float pr = (a2 / fmaxf(sqrtf(n2), 1e-12f)
                  + a3 / fmaxf(sqrtf(n3), 1e-12f)
                  + a4 / fmaxf(sqrtf(n4), 1e-12f)) * (1.0f / 3.0f);
        pr_sh[p][lane] = pr;
        float term = -(qv - rv) * pr * h0 + (qv * rv) * h1;
        float wsum = wred_sum(term);
        if (lane == 0) weight_sh[p] = wsum;
    }
    __syncthreads();

    // ---- finale: wave 0 does softmax over P, pooled, scores ----
    if (wv == 0) {
        float wt = (weight_sh[lane] + hb[0]) * 5.0f;   // /0.2
        float mx = wt;
#pragma unroll
        for (int off = 32; off > 0; off >>= 1) mx = fmaxf(mx, __shfl_xor(mx, off, 64));
        float e = expf(wt - mx);
        float wn = e / wred_sum(e);
        wsh[lane] = wn;
        float pooled = 0.f;
#pragma unroll 8
        for (int p = 0; p < PP; ++p) pooled += pr_sh[p][lane] * wsh[p];
        float s1 = wred_sum(qv * rv * p1w[lane]);
        float s2 = wred_sum((rv - qv) * pooled * p2w[lane]);
        if (lane == 0) out[b] = (s1 + p1b[0]) + 5.0f * (s2 + p2b[0]);
    }
}

extern "C" void kernel_launch(void* const* d_in, const int* in_sizes, int n_in,
                              void* d_out, int out_size, void* d_ws, size_t ws_size,
                              hipStream_t stream) {
    const int*   qry_id = (const int*)d_in[0];
    const int*   res_id = (const int*)d_in[1];
    const int*   path   = (const int*)d_in[2];
    const int*   mask   = (const int*)d_in[3];
    const float* img    = (const float*)d_in[4];
    const float* Ww     = (const float*)d_in[5];
    const float* Wb     = (const float*)d_in[6];
    const float* meta   = (const float*)d_in[7];
    const float* hw     = (const float*)d_in[8];
    const float* hb     = (const float*)d_in[9];
    const float* p1w    = (const float*)d_in[10];
    const float* p1b    = (const float*)d_in[11];
    const float* p2w    = (const float*)d_in[12];
    const float* p2b    = (const float*)d_in[13];

    float* rnorm = (float*)d_ws;          // 50000 floats
    float* out   = (float*)d_out;

    hipLaunchKernelGGL(k_meta_norm, dim3((META_N + 3) / 4), dim3(256), 0, stream,
                       meta, rnorm);
    hipLaunchKernelGGL(k_fused, dim3(BB), dim3(1024), 0, stream,
                       qry_id, res_id, path, mask, img, Ww, Wb, meta, rnorm,
                       hw, hb, p1w, p1b, p2w, p2b, out);
}

// Round 3
// 23.480 us; speedup vs baseline: 1.8883x; 1.3500x over previous
//
#include <hip/hip_runtime.h>

#define BB 256
#define PP 64
#define LL 16
#define DD 64
#define IMGF 512

__device__ __forceinline__ float wred_sum(float v) {
#pragma unroll
    for (int off = 32; off > 0; off >>= 1) v += __shfl_xor(v, off, 64);
    return v;
}

// sum across a 16-lane group (groups aligned on 16-lane boundaries)
__device__ __forceinline__ float gred_sum16(float v) {
    v += __shfl_xor(v, 1, 64);
    v += __shfl_xor(v, 2, 64);
    v += __shfl_xor(v, 4, 64);
    v += __shfl_xor(v, 8, 64);
    return v;
}

__device__ __forceinline__ float dot4(float4 a, float4 b) {
    return a.x * b.x + a.y * b.y + a.z * b.z + a.w * b.w;
}

// Single fused kernel: img GEMV + l2norm, path processing (inline row norms),
// softmax pooling, final scores. One block of 1024 threads (16 waves) per b.
// Path phase: each wave handles 4 p's IN PARALLEL via 16-lane groups; each
// lane holds float4 (4 of the 64 dims). Row l2norm = dot4 + 4-shuffle reduce.
__launch_bounds__(1024, 1)
__global__ void k_fused(const int* __restrict__ qry_id, const int* __restrict__ res_id,
                        const int* __restrict__ path, const int* __restrict__ mask,
                        const float* __restrict__ img, const float* __restrict__ Ww,
                        const float* __restrict__ Wb,
                        const float* __restrict__ meta,
                        const float* __restrict__ hw, const float* __restrict__ hb,
                        const float* __restrict__ p1w, const float* __restrict__ p1b,
                        const float* __restrict__ p2w, const float* __restrict__ p2b,
                        float* __restrict__ out) {
    __shared__ float fq[IMGF], fr[IMGF];         // staged image feature rows
    __shared__ float pq[16][DD], prt[16][DD];    // GEMV partials
    __shared__ float qf[DD], rf[DD];             // normalized features
    __shared__ float pr_sh[PP][DD];              // path_res
    __shared__ float weight_sh[PP];
    __shared__ float wsh[PP];

    int b = blockIdx.x;
    int tid = threadIdx.x;
    int lane = tid & 63;
    int wv = tid >> 6;        // 0..15
    int g = lane >> 4;        // 16-lane group within wave: 0..3
    int j = lane & 15;        // lane within group
    int p = wv * 4 + g;       // this group's path index

    // ---- prefetch this group's path indices+mask (1 int per lane, coalesced) ----
    int packed;
    {
        int pj = path[(b * PP + p) * LL + j];
        int mj = mask[(b * PP + p) * LL + j];
        packed = pj | (mj << 16);     // idx < 50000 < 65536
    }

    // ---- stage the two gathered image-feature rows (coalesced) ----
    {
        int qid = qry_id[b], rid = res_id[b];
        if (tid < IMGF) fq[tid] = img[(long long)qid * IMGF + tid];
        else            fr[tid - IMGF] = img[(long long)rid * IMGF + (tid - IMGF)];
    }
    __syncthreads();

    // ---- GEMV: output d = lane, k-slice = wv (32 k each) ----
    {
        float aq = 0.f, ar = 0.f;
        const float* wrow = Ww + lane * IMGF + wv * 32;
        const float* q0 = fq + wv * 32;
        const float* r0 = fr + wv * 32;
#pragma unroll
        for (int k = 0; k < 32; k += 4) {
            float4 w4 = *(const float4*)(wrow + k);
            aq += w4.x * q0[k] + w4.y * q0[k + 1] + w4.z * q0[k + 2] + w4.w * q0[k + 3];
            ar += w4.x * r0[k] + w4.y * r0[k + 1] + w4.z * r0[k + 2] + w4.w * r0[k + 3];
        }
        pq[wv][lane] = aq;
        prt[wv][lane] = ar;
    }
    __syncthreads();
    if (wv < 2) {
        float acc = Wb[lane];
#pragma unroll
        for (int s = 0; s < 16; ++s) acc += (wv ? prt[s][lane] : pq[s][lane]);
        float n = wred_sum(acc * acc);
        float v = acc / fmaxf(sqrtf(n), 1e-12f);
        (wv ? rf : qf)[lane] = v;
    }
    __syncthreads();

    // ---- path phase: group g handles p; lane j holds dims [4j, 4j+4) ----
    float4 pm[8];
#pragma unroll
    for (int k = 0; k < 8; ++k) pm[k] = make_float4(0.f, 0.f, 0.f, 0.f);
#pragma unroll
    for (int l = 0; l < LL; ++l) {
        int src = (lane & 48) | l;
        int im = __shfl(packed, src, 64);
        int m = im >> 16;
        if (m) {                                   // group-uniform predicate
            int idx = im & 0xFFFF;
            float4 v = *(const float4*)(meta + idx * DD + 4 * j);
            float ss = gred_sum16(dot4(v, v));
            float rn = 1.0f / fmaxf(sqrtf(ss), 1e-12f);
            pm[l >> 1].x += v.x * rn;
            pm[l >> 1].y += v.y * rn;
            pm[l >> 1].z += v.z * rn;
            pm[l >> 1].w += v.w * rn;
        }
    }
    float4 a2 = make_float4(0.f, 0.f, 0.f, 0.f);
    float4 a3 = a2, a4 = a2;
#pragma unroll
    for (int k = 0; k < 7; ++k) {
        a2.x += pm[k].x * pm[k + 1].x; a2.y += pm[k].y * pm[k + 1].y;
        a2.z += pm[k].z * pm[k + 1].z; a2.w += pm[k].w * pm[k + 1].w;
    }
#pragma unroll
    for (int k = 0; k < 6; ++k) {
        a3.x += pm[k].x * pm[k + 1].x * pm[k + 2].x;
        a3.y += pm[k].y * pm[k + 1].y * pm[k + 2].y;
        a3.z += pm[k].z * pm[k + 1].z * pm[k + 2].z;
        a3.w += pm[k].w * pm[k + 1].w * pm[k + 2].w;
    }
#pragma unroll
    for (int k = 0; k < 5; ++k) {
        a4.x += pm[k].x * pm[k + 1].x * pm[k + 2].x * pm[k + 3].x;
        a4.y += pm[k].y * pm[k + 1].y * pm[k + 2].y * pm[k + 3].y;
        a4.z += pm[k].z * pm[k + 1].z * pm[k + 2].z * pm[k + 3].z;
        a4.w += pm[k].w * pm[k + 1].w * pm[k + 2].w * pm[k + 3].w;
    }
    a2.x *= (1.0f / 7.0f); a2.y *= (1.0f / 7.0f); a2.z *= (1.0f / 7.0f); a2.w *= (1.0f / 7.0f);
    a3.x *= (1.0f / 6.0f); a3.y *= (1.0f / 6.0f); a3.z *= (1.0f / 6.0f); a3.w *= (1.0f / 6.0f);
    a4.x *= (1.0f / 5.0f); a4.y *= (1.0f / 5.0f); a4.z *= (1.0f / 5.0f); a4.w *= (1.0f / 5.0f);
    float n2 = gred_sum16(dot4(a2, a2));
    float n3 = gred_sum16(dot4(a3, a3));
    float n4 = gred_sum16(dot4(a4, a4));
    float i2n = 1.0f / fmaxf(sqrtf(n2), 1e-12f);
    float i3n = 1.0f / fmaxf(sqrtf(n3), 1e-12f);
    float i4n = 1.0f / fmaxf(sqrtf(n4), 1e-12f);
    float4 pr;
    pr.x = (a2.x * i2n + a3.x * i3n + a4.x * i4n) * (1.0f / 3.0f);
    pr.y = (a2.y * i2n + a3.y * i3n + a4.y * i4n) * (1.0f / 3.0f);
    pr.z = (a2.z * i2n + a3.z * i3n + a4.z * i4n) * (1.0f / 3.0f);
    pr.w = (a2.w * i2n + a3.w * i3n + a4.w * i4n) * (1.0f / 3.0f);
    ((float4*)pr_sh[p])[j] = pr;

    {
        float4 q4 = ((const float4*)qf)[j];
        float4 r4 = ((const float4*)rf)[j];
        float4 h0 = ((const float4*)hw)[j];
        float4 h1 = ((const float4*)(hw + DD))[j];
        float t = -(q4.x - r4.x) * pr.x * h0.x + (q4.x * r4.x) * h1.x
                  - (q4.y - r4.y) * pr.y * h0.y + (q4.y * r4.y) * h1.y
                  - (q4.z - r4.z) * pr.z * h0.z + (q4.z * r4.z) * h1.z
                  - (q4.w - r4.w) * pr.w * h0.w + (q4.w * r4.w) * h1.w;
        t = gred_sum16(t);
        if (j == 0) weight_sh[p] = t;
    }
    __syncthreads();

    // ---- finale: wave 0 does softmax over P, pooled, scores ----
    if (wv == 0) {
        float wt = (weight_sh[lane] + hb[0]) * 5.0f;   // /0.2
        float mx = wt;
#pragma unroll
        for (int off = 32; off > 0; off >>= 1) mx = fmaxf(mx, __shfl_xor(mx, off, 64));
        float e = expf(wt - mx);
        float wn = e / wred_sum(e);
        wsh[lane] = wn;
        float pooled = 0.f;
#pragma unroll 8
        for (int pp2 = 0; pp2 < PP; ++pp2) pooled += pr_sh[pp2][lane] * wsh[pp2];
        float qv = qf[lane], rv = rf[lane];
        float s1 = wred_sum(qv * rv * p1w[lane]);
        float s2 = wred_sum((rv - qv) * pooled * p2w[lane]);
        if (lane == 0) out[b] = (s1 + p1b[0]) + 5.0f * (s2 + p2b[0]);
    }
}

extern "C" void kernel_launch(void* const* d_in, const int* in_sizes, int n_in,
                              void* d_out, int out_size, void* d_ws, size_t ws_size,
                              hipStream_t stream) {
    const int*   qry_id = (const int*)d_in[0];
    const int*   res_id = (const int*)d_in[1];
    const int*   path   = (const int*)d_in[2];
    const int*   mask   = (const int*)d_in[3];
    const float* img    = (const float*)d_in[4];
    const float* Ww     = (const float*)d_in[5];
    const float* Wb     = (const float*)d_in[6];
    const float* meta   = (const float*)d_in[7];
    const float* hw     = (const float*)d_in[8];
    const float* hb     = (const float*)d_in[9];
    const float* p1w    = (const float*)d_in[10];
    const float* p1b    = (const float*)d_in[11];
    const float* p2w    = (const float*)d_in[12];
    const float* p2b    = (const float*)d_in[13];

    float* out = (float*)d_out;

    hipLaunchKernelGGL(k_fused, dim3(BB), dim3(1024), 0, stream,
                       qry_id, res_id, path, mask, img, Ww, Wb, meta,
                       hw, hb, p1w, p1b, p2w, p2b, out);
}

// Round 7
// 20.528 us; speedup vs baseline: 2.1599x; 1.1438x over previous
//
#include <hip/hip_runtime.h>

#define BB 256
#define PP 64
#define LL 16
#define DD 64
#define IMGF 512

__device__ __forceinline__ float wred_sum(float v) {
#pragma unroll
    for (int off = 32; off > 0; off >>= 1) v += __shfl_xor(v, off, 64);
    return v;
}

// sum across a 16-lane group (groups aligned on 16-lane boundaries)
__device__ __forceinline__ float gred_sum16(float v) {
    v += __shfl_xor(v, 1, 64);
    v += __shfl_xor(v, 2, 64);
    v += __shfl_xor(v, 4, 64);
    v += __shfl_xor(v, 8, 64);
    return v;
}

__device__ __forceinline__ float dot4(float4 a, float4 b) {
    return a.x * b.x + a.y * b.y + a.z * b.z + a.w * b.w;
}

// Single fused kernel, one 1024-thread block (16 waves) per batch element b.
// GEMV: 16-lane group per output row, contiguous striding (coalesced).
// Path: 16-lane group per p, lane j holds dims [4j,4j+4); gathers batched
// 8-deep with mask folded multiplicatively (no branch -> pipelined loads).
__launch_bounds__(1024, 1)
__global__ void k_fused(const int* __restrict__ qry_id, const int* __restrict__ res_id,
                        const int* __restrict__ path, const int* __restrict__ mask,
                        const float* __restrict__ img, const float* __restrict__ Ww,
                        const float* __restrict__ Wb,
                        const float* __restrict__ meta,
                        const float* __restrict__ hw, const float* __restrict__ hb,
                        const float* __restrict__ p1w, const float* __restrict__ p1b,
                        const float* __restrict__ p2w, const float* __restrict__ p2b,
                        float* __restrict__ out) {
    __shared__ float fq[IMGF], fr[IMGF];   // staged image feature rows
    __shared__ float pq_row[DD], pr_row[DD]; // GEMV row dots (pre-norm)
    __shared__ float qf[DD], rf[DD];       // normalized features
    __shared__ float pr_sh[PP][DD];        // path_res
    __shared__ float weight_sh[PP];
    __shared__ float wsh[PP];

    int b = blockIdx.x;
    int tid = threadIdx.x;
    int lane = tid & 63;
    int wv = tid >> 6;        // 0..15
    int g = lane >> 4;        // 16-lane group in wave: 0..3
    int j = lane & 15;        // lane within group
    int p = wv * 4 + g;       // this group's path index

    // ---- prefetch this group's path indices+mask (coalesced, 1 int/lane) ----
    int packed;
    {
        int pj = path[(b * PP + p) * LL + j];
        int mj = mask[(b * PP + p) * LL + j];
        packed = pj | (mj << 16);     // idx < 50000 < 65536
    }

    // ---- stage the two gathered image-feature rows (coalesced) ----
    {
        int qid = qry_id[b], rid = res_id[b];
        if (tid < IMGF) fq[tid] = img[(long long)qid * IMGF + tid];
        else            fr[tid - IMGF] = img[(long long)rid * IMGF + (tid - IMGF)];
    }
    __syncthreads();

    // ---- GEMV: group (wv,g) owns output row; contiguous float4 striding ----
    {
        int row = p;                                  // 16 waves * 4 groups = 64 rows
        const float4* wr = (const float4*)(Ww + row * IMGF);
        const float4* q4p = (const float4*)fq;
        const float4* r4p = (const float4*)fr;
        float aq = 0.f, ar = 0.f;
#pragma unroll
        for (int i = 0; i < 8; ++i) {
            float4 w4 = wr[i * 16 + j];               // group: 256B contiguous
            float4 q4 = q4p[i * 16 + j];
            float4 r4 = r4p[i * 16 + j];
            aq += dot4(w4, q4);
            ar += dot4(w4, r4);
        }
        aq = gred_sum16(aq);
        ar = gred_sum16(ar);
        if (j == 0) { pq_row[row] = aq; pr_row[row] = ar; }
    }
    __syncthreads();
    if (wv < 2) {                      // finish norms while others start gathers
        float acc = Wb[lane] + (wv ? pr_row[lane] : pq_row[lane]);
        float n = wred_sum(acc * acc);
        float v = acc / fmaxf(sqrtf(n), 1e-12f);
        (wv ? rf : qf)[lane] = v;
    }

    // ---- path phase: group g handles p; lane j holds dims [4j,4j+4) ----
    float4 pm[8];
#pragma unroll
    for (int k = 0; k < 8; ++k) pm[k] = make_float4(0.f, 0.f, 0.f, 0.f);
#pragma unroll
    for (int c = 0; c < 2; ++c) {
        int idxs[8]; float ms[8]; float4 v[8];
#pragma unroll
        for (int l = 0; l < 8; ++l) {
            int im = __shfl(packed, (lane & 48) | (c * 8 + l), 64);
            idxs[l] = im & 0xFFFF;
            ms[l] = (float)(im >> 16);
        }
#pragma unroll
        for (int l = 0; l < 8; ++l) v[l] = *(const float4*)(meta + idxs[l] * DD + 4 * j);
#pragma unroll
        for (int l = 0; l < 8; ++l) {
            float ss = gred_sum16(dot4(v[l], v[l]));
            float rn = ms[l] / fmaxf(sqrtf(ss), 1e-12f);   // mask folded in
            int k = (c * 8 + l) >> 1;
            pm[k].x += v[l].x * rn;
            pm[k].y += v[l].y * rn;
            pm[k].z += v[l].z * rn;
            pm[k].w += v[l].w * rn;
        }
    }
    float4 a2 = make_float4(0.f, 0.f, 0.f, 0.f);
    float4 a3 = a2, a4 = a2;
#pragma unroll
    for (int k = 0; k < 7; ++k) {
        a2.x += pm[k].x * pm[k + 1].x; a2.y += pm[k].y * pm[k + 1].y;
        a2.z += pm[k].z * pm[k + 1].z; a2.w += pm[k].w * pm[k + 1].w;
    }
#pragma unroll
    for (int k = 0; k < 6; ++k) {
        a3.x += pm[k].x * pm[k + 1].x * pm[k + 2].x;
        a3.y += pm[k].y * pm[k + 1].y * pm[k + 2].y;
        a3.z += pm[k].z * pm[k + 1].z * pm[k + 2].z;
        a3.w += pm[k].w * pm[k + 1].w * pm[k + 2].w;
    }
#pragma unroll
    for (int k = 0; k < 5; ++k) {
        a4.x += pm[k].x * pm[k + 1].x * pm[k + 2].x * pm[k + 3].x;
        a4.y += pm[k].y * pm[k + 1].y * pm[k + 2].y * pm[k + 3].y;
        a4.z += pm[k].z * pm[k + 1].z * pm[k + 2].z * pm[k + 3].z;
        a4.w += pm[k].w * pm[k + 1].w * pm[k + 2].w * pm[k + 3].w;
    }
    a2.x *= (1.0f / 7.0f); a2.y *= (1.0f / 7.0f); a2.z *= (1.0f / 7.0f); a2.w *= (1.0f / 7.0f);
    a3.x *= (1.0f / 6.0f); a3.y *= (1.0f / 6.0f); a3.z *= (1.0f / 6.0f); a3.w *= (1.0f / 6.0f);
    a4.x *= (1.0f / 5.0f); a4.y *= (1.0f / 5.0f); a4.z *= (1.0f / 5.0f); a4.w *= (1.0f / 5.0f);
    float n2 = gred_sum16(dot4(a2, a2));
    float n3 = gred_sum16(dot4(a3, a3));
    float n4 = gred_sum16(dot4(a4, a4));
    float i2n = 1.0f / fmaxf(sqrtf(n2), 1e-12f);
    float i3n = 1.0f / fmaxf(sqrtf(n3), 1e-12f);
    float i4n = 1.0f / fmaxf(sqrtf(n4), 1e-12f);
    float4 pr;
    pr.x = (a2.x * i2n + a3.x * i3n + a4.x * i4n) * (1.0f / 3.0f);
    pr.y = (a2.y * i2n + a3.y * i3n + a4.y * i4n) * (1.0f / 3.0f);
    pr.z = (a2.z * i2n + a3.z * i3n + a4.z * i4n) * (1.0f / 3.0f);
    pr.w = (a2.w * i2n + a3.w * i3n + a4.w * i4n) * (1.0f / 3.0f);
    ((float4*)pr_sh[p])[j] = pr;
    __syncthreads();   // qf/rf written (wv<2 did it pre-gather) + pr_sh done

    {
        float4 q4 = ((const float4*)qf)[j];
        float4 r4 = ((const float4*)rf)[j];
        float4 h0 = ((const float4*)hw)[j];
        float4 h1 = ((const float4*)(hw + DD))[j];
        float t = -(q4.x - r4.x) * pr.x * h0.x + (q4.x * r4.x) * h1.x
                  - (q4.y - r4.y) * pr.y * h0.y + (q4.y * r4.y) * h1.y
                  - (q4.z - r4.z) * pr.z * h0.z + (q4.z * r4.z) * h1.z
                  - (q4.w - r4.w) * pr.w * h0.w + (q4.w * r4.w) * h1.w;
        t = gred_sum16(t);
        if (j == 0) weight_sh[p] = t;
    }
    __syncthreads();

    // ---- finale: wave 0 does softmax over P, pooled, scores ----
    if (wv == 0) {
        float wt = (weight_sh[lane] + hb[0]) * 5.0f;   // /0.2
        float mx = wt;
#pragma unroll
        for (int off = 32; off > 0; off >>= 1) mx = fmaxf(mx, __shfl_xor(mx, off, 64));
        float e = expf(wt - mx);
        float wn = e / wred_sum(e);
        wsh[lane] = wn;
        float pooled = 0.f;
#pragma unroll 8
        for (int pp2 = 0; pp2 < PP; ++pp2) pooled += pr_sh[pp2][lane] * wsh[pp2];
        float qv = qf[lane], rv = rf[lane];
        float s1 = wred_sum(qv * rv * p1w[lane]);
        float s2 = wred_sum((rv - qv) * pooled * p2w[lane]);
        if (lane == 0) out[b] = (s1 + p1b[0]) + 5.0f * (s2 + p2b[0]);
    }
}

extern "C" void kernel_launch(void* const* d_in, const int* in_sizes, int n_in,
                              void* d_out, int out_size, void* d_ws, size_t ws_size,
                              hipStream_t stream) {
    const int*   qry_id = (const int*)d_in[0];
    const int*   res_id = (const int*)d_in[1];
    const int*   path   = (const int*)d_in[2];
    const int*   mask   = (const int*)d_in[3];
    const float* img    = (const float*)d_in[4];
    const float* Ww     = (const float*)d_in[5];
    const float* Wb     = (const float*)d_in[6];
    const float* meta   = (const float*)d_in[7];
    const float* hw     = (const float*)d_in[8];
    const float* hb     = (const float*)d_in[9];
    const float* p1w    = (const float*)d_in[10];
    const float* p1b    = (const float*)d_in[11];
    const float* p2w    = (const float*)d_in[12];
    const float* p2b    = (const float*)d_in[13];

    float* out = (float*)d_out;

    hipLaunchKernelGGL(k_fused, dim3(BB), dim3(1024), 0, stream,
                       qry_id, res_id, path, mask, img, Ww, Wb, meta,
                       hw, hb, p1w, p1b, p2w, p2b, out);
}

// Round 9
// 18.437 us; speedup vs baseline: 2.4048x; 1.1134x over previous
//
#include <hip/hip_runtime.h>

#define BB 256
#define PP 64
#define LL 16
#define DD 64
#define IMGF 512

__device__ __forceinline__ float wred_sum(float v) {
#pragma unroll
    for (int off = 32; off > 0; off >>= 1) v += __shfl_xor(v, off, 64);
    return v;
}

// sum across a 16-lane group (groups aligned on 16-lane boundaries)
__device__ __forceinline__ float gred_sum16(float v) {
    v += __shfl_xor(v, 1, 64);
    v += __shfl_xor(v, 2, 64);
    v += __shfl_xor(v, 4, 64);
    v += __shfl_xor(v, 8, 64);
    return v;
}

__device__ __forceinline__ float dot4(float4 a, float4 b) {
    return a.x * b.x + a.y * b.y + a.z * b.z + a.w * b.w;
}

// 1/max(sqrt(n),1e-12) ~= rsqrt(max(n,1e-24)): single v_rsq_f32, ~2ulp.
// abs threshold is 1.14e-2 so this is free; guard keeps 0-vectors -> 0.
__device__ __forceinline__ float rnorm_fast(float n) {
    return rsqrtf(fmaxf(n, 1e-24f));
}

// Single fused kernel, one 1024-thread block (16 waves) per batch element b.
// GEMV: 16-lane group per output row, contiguous striding (coalesced).
// Path: 16-lane group per p, lane j holds dims [4j,4j+4); gathers batched
// 8-deep with mask folded multiplicatively; all norms via v_rsq_f32.
__launch_bounds__(1024, 1)
__global__ void k_fused(const int* __restrict__ qry_id, const int* __restrict__ res_id,
                        const int* __restrict__ path, const int* __restrict__ mask,
                        const float* __restrict__ img, const float* __restrict__ Ww,
                        const float* __restrict__ Wb,
                        const float* __restrict__ meta,
                        const float* __restrict__ hw, const float* __restrict__ hb,
                        const float* __restrict__ p1w, const float* __restrict__ p1b,
                        const float* __restrict__ p2w, const float* __restrict__ p2b,
                        float* __restrict__ out) {
    __shared__ float fq[IMGF], fr[IMGF];     // staged image feature rows
    __shared__ float pq_row[DD], pr_row[DD]; // GEMV row dots (pre-norm)
    __shared__ float qf[DD], rf[DD];         // normalized features
    __shared__ float pr_sh[PP][DD];          // path_res
    __shared__ float weight_sh[PP];
    __shared__ float wsh[PP];

    int b = blockIdx.x;
    int tid = threadIdx.x;
    int lane = tid & 63;
    int wv = tid >> 6;        // 0..15
    int g = lane >> 4;        // 16-lane group in wave: 0..3
    int j = lane & 15;        // lane within group
    int p = wv * 4 + g;       // this group's path index

    // ---- prefetch this group's path indices+mask (coalesced, 1 int/lane) ----
    int packed;
    {
        int pj = path[(b * PP + p) * LL + j];
        int mj = mask[(b * PP + p) * LL + j];
        packed = pj | (mj << 16);     // idx < 50000 < 65536
    }

    // ---- stage the two gathered image-feature rows (coalesced) ----
    {
        int qid = qry_id[b], rid = res_id[b];
        if (tid < IMGF) fq[tid] = img[(long long)qid * IMGF + tid];
        else            fr[tid - IMGF] = img[(long long)rid * IMGF + (tid - IMGF)];
    }
    __syncthreads();

    // ---- GEMV: group (wv,g) owns output row; contiguous float4 striding ----
    {
        int row = p;                                  // 16 waves * 4 groups = 64 rows
        const float4* wr = (const float4*)(Ww + row * IMGF);
        const float4* q4p = (const float4*)fq;
        const float4* r4p = (const float4*)fr;
        float aq = 0.f, ar = 0.f;
#pragma unroll
        for (int i = 0; i < 8; ++i) {
            float4 w4 = wr[i * 16 + j];               // group: 256B contiguous
            float4 q4 = q4p[i * 16 + j];
            float4 r4 = r4p[i * 16 + j];
            aq += dot4(w4, q4);
            ar += dot4(w4, r4);
        }
        aq = gred_sum16(aq);
        ar = gred_sum16(ar);
        if (j == 0) { pq_row[row] = aq; pr_row[row] = ar; }
    }
    __syncthreads();
    if (wv < 2) {                      // finish norms while others start gathers
        float acc = Wb[lane] + (wv ? pr_row[lane] : pq_row[lane]);
        float n = wred_sum(acc * acc);
        float v = acc * rnorm_fast(n);
        (wv ? rf : qf)[lane] = v;
    }

    // ---- path phase: group g handles p; lane j holds dims [4j,4j+4) ----
    float4 pm[8];
#pragma unroll
    for (int k = 0; k < 8; ++k) pm[k] = make_float4(0.f, 0.f, 0.f, 0.f);
#pragma unroll
    for (int c = 0; c < 2; ++c) {
        int idxs[8]; float ms[8]; float4 v[8];
#pragma unroll
        for (int l = 0; l < 8; ++l) {
            int im = __shfl(packed, (lane & 48) | (c * 8 + l), 64);
            idxs[l] = im & 0xFFFF;
            ms[l] = (float)(im >> 16);
        }
#pragma unroll
        for (int l = 0; l < 8; ++l) v[l] = *(const float4*)(meta + idxs[l] * DD + 4 * j);
#pragma unroll
        for (int l = 0; l < 8; ++l) {
            float ss = gred_sum16(dot4(v[l], v[l]));
            float rn = ms[l] * rnorm_fast(ss);         // mask folded in
            int k = (c * 8 + l) >> 1;
            pm[k].x += v[l].x * rn;
            pm[k].y += v[l].y * rn;
            pm[k].z += v[l].z * rn;
            pm[k].w += v[l].w * rn;
        }
    }
    float4 a2 = make_float4(0.f, 0.f, 0.f, 0.f);
    float4 a3 = a2, a4 = a2;
#pragma unroll
    for (int k = 0; k < 7; ++k) {
        a2.x += pm[k].x * pm[k + 1].x; a2.y += pm[k].y * pm[k + 1].y;
        a2.z += pm[k].z * pm[k + 1].z; a2.w += pm[k].w * pm[k + 1].w;
    }
#pragma unroll
    for (int k = 0; k < 6; ++k) {
        a3.x += pm[k].x * pm[k + 1].x * pm[k + 2].x;
        a3.y += pm[k].y * pm[k + 1].y * pm[k + 2].y;
        a3.z += pm[k].z * pm[k + 1].z * pm[k + 2].z;
        a3.w += pm[k].w * pm[k + 1].w * pm[k + 2].w;
    }
#pragma unroll
    for (int k = 0; k < 5; ++k) {
        a4.x += pm[k].x * pm[k + 1].x * pm[k + 2].x * pm[k + 3].x;
        a4.y += pm[k].y * pm[k + 1].y * pm[k + 2].y * pm[k + 3].y;
        a4.z += pm[k].z * pm[k + 1].z * pm[k + 2].z * pm[k + 3].z;
        a4.w += pm[k].w * pm[k + 1].w * pm[k + 2].w * pm[k + 3].w;
    }
    a2.x *= (1.0f / 7.0f); a2.y *= (1.0f / 7.0f); a2.z *= (1.0f / 7.0f); a2.w *= (1.0f / 7.0f);
    a3.x *= (1.0f / 6.0f); a3.y *= (1.0f / 6.0f); a3.z *= (1.0f / 6.0f); a3.w *= (1.0f / 6.0f);
    a4.x *= (1.0f / 5.0f); a4.y *= (1.0f / 5.0f); a4.z *= (1.0f / 5.0f); a4.w *= (1.0f / 5.0f);
    float i2n = rnorm_fast(gred_sum16(dot4(a2, a2)));
    float i3n = rnorm_fast(gred_sum16(dot4(a3, a3)));
    float i4n = rnorm_fast(gred_sum16(dot4(a4, a4)));
    float4 pr;
    pr.x = (a2.x * i2n + a3.x * i3n + a4.x * i4n) * (1.0f / 3.0f);
    pr.y = (a2.y * i2n + a3.y * i3n + a4.y * i4n) * (1.0f / 3.0f);
    pr.z = (a2.z * i2n + a3.z * i3n + a4.z * i4n) * (1.0f / 3.0f);
    pr.w = (a2.w * i2n + a3.w * i3n + a4.w * i4n) * (1.0f / 3.0f);
    ((float4*)pr_sh[p])[j] = pr;
    __syncthreads();   // qf/rf written (wv<2 did it pre-gather) + pr_sh done

    {
        float4 q4 = ((const float4*)qf)[j];
        float4 r4 = ((const float4*)rf)[j];
        float4 h0 = ((const float4*)hw)[j];
        float4 h1 = ((const float4*)(hw + DD))[j];
        float t = -(q4.x - r4.x) * pr.x * h0.x + (q4.x * r4.x) * h1.x
                  - (q4.y - r4.y) * pr.y * h0.y + (q4.y * r4.y) * h1.y
                  - (q4.z - r4.z) * pr.z * h0.z + (q4.z * r4.z) * h1.z
                  - (q4.w - r4.w) * pr.w * h0.w + (q4.w * r4.w) * h1.w;
        t = gred_sum16(t);
        if (j == 0) weight_sh[p] = t;
    }
    __syncthreads();

    // ---- finale: wave 0 does softmax over P, pooled, scores ----
    if (wv == 0) {
        float wt = (weight_sh[lane] + hb[0]) * 5.0f;   // /0.2
        float mx = wt;
#pragma unroll
        for (int off = 32; off > 0; off >>= 1) mx = fmaxf(mx, __shfl_xor(mx, off, 64));
        float e = __expf(wt - mx);
        float wn = e / wred_sum(e);
        wsh[lane] = wn;
        float pooled = 0.f;
#pragma unroll 8
        for (int pp2 = 0; pp2 < PP; ++pp2) pooled += pr_sh[pp2][lane] * wsh[pp2];
        float qv = qf[lane], rv = rf[lane];
        float s1 = wred_sum(qv * rv * p1w[lane]);
        float s2 = wred_sum((rv - qv) * pooled * p2w[lane]);
        if (lane == 0) out[b] = (s1 + p1b[0]) + 5.0f * (s2 + p2b[0]);
    }
}

extern "C" void kernel_launch(void* const* d_in, const int* in_sizes, int n_in,
                              void* d_out, int out_size, void* d_ws, size_t ws_size,
                              hipStream_t stream) {
    const int*   qry_id = (const int*)d_in[0];
    const int*   res_id = (const int*)d_in[1];
    const int*   path   = (const int*)d_in[2];
    const int*   mask   = (const int*)d_in[3];
    const float* img    = (const float*)d_in[4];
    const float* Ww     = (const float*)d_in[5];
    const float* Wb     = (const float*)d_in[6];
    const float* meta   = (const float*)d_in[7];
    const float* hw     = (const float*)d_in[8];
    const float* hb     = (const float*)d_in[9];
    const float* p1w    = (const float*)d_in[10];
    const float* p1b    = (const float*)d_in[11];
    const float* p2w    = (const float*)d_in[12];
    const float* p2b    = (const float*)d_in[13];

    float* out = (float*)d_out;

    hipLaunchKernelGGL(k_fused, dim3(BB), dim3(1024), 0, stream,
                       qry_id, res_id, path, mask, img, Ww, Wb, meta,
                       hw, hb, p1w, p1b, p2w, p2b, out);
}

// Round 10
// 15.521 us; speedup vs baseline: 2.8567x; 1.1879x over previous
//
#include <hip/hip_runtime.h>

#define BB 256
#define PP 64
#define LL 16
#define DD 64
#define IMGF 512

__device__ __forceinline__ float wred_sum(float v) {
#pragma unroll
    for (int off = 32; off > 0; off >>= 1) v += __shfl_xor(v, off, 64);
    return v;
}

// sum across a 16-lane group (groups aligned on 16-lane boundaries)
__device__ __forceinline__ float gred_sum16(float v) {
    v += __shfl_xor(v, 1, 64);
    v += __shfl_xor(v, 2, 64);
    v += __shfl_xor(v, 4, 64);
    v += __shfl_xor(v, 8, 64);
    return v;
}

__device__ __forceinline__ float dot4(float4 a, float4 b) {
    return a.x * b.x + a.y * b.y + a.z * b.z + a.w * b.w;
}

// 1/max(sqrt(n),1e-12) ~= rsqrt(max(n,1e-24)): single v_rsq_f32, ~2ulp.
// abs threshold is 1.14e-2 so this is free; guard keeps 0-vectors -> 0.
__device__ __forceinline__ float rnorm_fast(float n) {
    return rsqrtf(fmaxf(n, 1e-24f));
}

// Single fused kernel, one 1024-thread block (16 waves) per batch element b.
// GEMV: 16-lane group per output row, contiguous striding (coalesced).
// Path: 16-lane group per p, lane j holds dims [4j,4j+4); gathers batched
// 8-deep; masked rows redirect to row 0 (L1-hot) so ~50% of gather
// instances never touch L2/L3; mask folded multiplicatively (exact zeros).
__launch_bounds__(1024, 1)
__global__ void k_fused(const int* __restrict__ qry_id, const int* __restrict__ res_id,
                        const int* __restrict__ path, const int* __restrict__ mask,
                        const float* __restrict__ img, const float* __restrict__ Ww,
                        const float* __restrict__ Wb,
                        const float* __restrict__ meta,
                        const float* __restrict__ hw, const float* __restrict__ hb,
                        const float* __restrict__ p1w, const float* __restrict__ p1b,
                        const float* __restrict__ p2w, const float* __restrict__ p2b,
                        float* __restrict__ out) {
    __shared__ float fq[IMGF], fr[IMGF];     // staged image feature rows
    __shared__ float pq_row[DD], pr_row[DD]; // GEMV row dots (pre-norm)
    __shared__ float qf[DD], rf[DD];         // normalized features
    __shared__ float pr_sh[PP][DD];          // path_res
    __shared__ float weight_sh[PP];
    __shared__ float wsh[PP];

    int b = blockIdx.x;
    int tid = threadIdx.x;
    int lane = tid & 63;
    int wv = tid >> 6;        // 0..15
    int g = lane >> 4;        // 16-lane group in wave: 0..3
    int j = lane & 15;        // lane within group
    int p = wv * 4 + g;       // this group's path index

    // ---- prefetch this group's path indices+mask (coalesced, 1 int/lane) ----
    int packed;
    {
        int pj = path[(b * PP + p) * LL + j];
        int mj = mask[(b * PP + p) * LL + j];
        packed = pj | (mj << 16);     // idx < 50000 < 65536
    }

    // ---- stage the two gathered image-feature rows (coalesced) ----
    {
        int qid = qry_id[b], rid = res_id[b];
        if (tid < IMGF) fq[tid] = img[(long long)qid * IMGF + tid];
        else            fr[tid - IMGF] = img[(long long)rid * IMGF + (tid - IMGF)];
    }
    __syncthreads();

    // ---- GEMV: group (wv,g) owns output row; contiguous float4 striding ----
    {
        int row = p;                                  // 16 waves * 4 groups = 64 rows
        const float4* wr = (const float4*)(Ww + row * IMGF);
        const float4* q4p = (const float4*)fq;
        const float4* r4p = (const float4*)fr;
        float aq = 0.f, ar = 0.f;
#pragma unroll
        for (int i = 0; i < 8; ++i) {
            float4 w4 = wr[i * 16 + j];               // group: 256B contiguous
            float4 q4 = q4p[i * 16 + j];
            float4 r4 = r4p[i * 16 + j];
            aq += dot4(w4, q4);
            ar += dot4(w4, r4);
        }
        aq = gred_sum16(aq);
        ar = gred_sum16(ar);
        if (j == 0) { pq_row[row] = aq; pr_row[row] = ar; }
    }
    __syncthreads();
    if (wv < 2) {                      // finish norms while others start gathers
        float acc = Wb[lane] + (wv ? pr_row[lane] : pq_row[lane]);
        float n = wred_sum(acc * acc);
        float v = acc * rnorm_fast(n);
        (wv ? rf : qf)[lane] = v;
    }

    // ---- path phase: group g handles p; lane j holds dims [4j,4j+4) ----
    float4 pm[8];
#pragma unroll
    for (int k = 0; k < 8; ++k) pm[k] = make_float4(0.f, 0.f, 0.f, 0.f);
#pragma unroll
    for (int c = 0; c < 2; ++c) {
        int idxs[8]; float ms[8]; float4 v[8];
#pragma unroll
        for (int l = 0; l < 8; ++l) {
            int im = __shfl(packed, (lane & 48) | (c * 8 + l), 64);
            int m = im >> 16;
            idxs[l] = m ? (im & 0xFFFF) : 0;   // masked -> row 0 (L1-hot dummy)
            ms[l] = (float)m;
        }
#pragma unroll
        for (int l = 0; l < 8; ++l) v[l] = *(const float4*)(meta + idxs[l] * DD + 4 * j);
#pragma unroll
        for (int l = 0; l < 8; ++l) {
            float ss = gred_sum16(dot4(v[l], v[l]));
            float rn = ms[l] * rnorm_fast(ss);         // mask folded in
            int k = (c * 8 + l) >> 1;
            pm[k].x += v[l].x * rn;
            pm[k].y += v[l].y * rn;
            pm[k].z += v[l].z * rn;
            pm[k].w += v[l].w * rn;
        }
    }
    float4 a2 = make_float4(0.f, 0.f, 0.f, 0.f);
    float4 a3 = a2, a4 = a2;
#pragma unroll
    for (int k = 0; k < 7; ++k) {
        a2.x += pm[k].x * pm[k + 1].x; a2.y += pm[k].y * pm[k + 1].y;
        a2.z += pm[k].z * pm[k + 1].z; a2.w += pm[k].w * pm[k + 1].w;
    }
#pragma unroll
    for (int k = 0; k < 6; ++k) {
        a3.x += pm[k].x * pm[k + 1].x * pm[k + 2].x;
        a3.y += pm[k].y * pm[k + 1].y * pm[k + 2].y;
        a3.z += pm[k].z * pm[k + 1].z * pm[k + 2].z;
        a3.w += pm[k].w * pm[k + 1].w * pm[k + 2].w;
    }
#pragma unroll
    for (int k = 0; k < 5; ++k) {
        a4.x += pm[k].x * pm[k + 1].x * pm[k + 2].x * pm[k + 3].x;
        a4.y += pm[k].y * pm[k + 1].y * pm[k + 2].y * pm[k + 3].y;
        a4.z += pm[k].z * pm[k + 1].z * pm[k + 2].z * pm[k + 3].z;
        a4.w += pm[k].w * pm[k + 1].w * pm[k + 2].w * pm[k + 3].w;
    }
    a2.x *= (1.0f / 7.0f); a2.y *= (1.0f / 7.0f); a2.z *= (1.0f / 7.0f); a2.w *= (1.0f / 7.0f);
    a3.x *= (1.0f / 6.0f); a3.y *= (1.0f / 6.0f); a3.z *= (1.0f / 6.0f); a3.w *= (1.0f / 6.0f);
    a4.x *= (1.0f / 5.0f); a4.y *= (1.0f / 5.0f); a4.z *= (1.0f / 5.0f); a4.w *= (1.0f / 5.0f);
    float i2n = rnorm_fast(gred_sum16(dot4(a2, a2)));
    float i3n = rnorm_fast(gred_sum16(dot4(a3, a3)));
    float i4n = rnorm_fast(gred_sum16(dot4(a4, a4)));
    float4 pr;
    pr.x = (a2.x * i2n + a3.x * i3n + a4.x * i4n) * (1.0f / 3.0f);
    pr.y = (a2.y * i2n + a3.y * i3n + a4.y * i4n) * (1.0f / 3.0f);
    pr.z = (a2.z * i2n + a3.z * i3n + a4.z * i4n) * (1.0f / 3.0f);
    pr.w = (a2.w * i2n + a3.w * i3n + a4.w * i4n) * (1.0f / 3.0f);
    ((float4*)pr_sh[p])[j] = pr;
    __syncthreads();   // qf/rf written (wv<2 did it pre-gather) + pr_sh done

    {
        float4 q4 = ((const float4*)qf)[j];
        float4 r4 = ((const float4*)rf)[j];
        float4 h0 = ((const float4*)hw)[j];
        float4 h1 = ((const float4*)(hw + DD))[j];
        float t = -(q4.x - r4.x) * pr.x * h0.x + (q4.x * r4.x) * h1.x
                  - (q4.y - r4.y) * pr.y * h0.y + (q4.y * r4.y) * h1.y
                  - (q4.z - r4.z) * pr.z * h0.z + (q4.z * r4.z) * h1.z
                  - (q4.w - r4.w) * pr.w * h0.w + (q4.w * r4.w) * h1.w;
        t = gred_sum16(t);
        if (j == 0) weight_sh[p] = t;
    }
    __syncthreads();

    // ---- finale: wave 0 does softmax over P, pooled, scores ----
    if (wv == 0) {
        float wt = (weight_sh[lane] + hb[0]) * 5.0f;   // /0.2
        float mx = wt;
#pragma unroll
        for (int off = 32; off > 0; off >>= 1) mx = fmaxf(mx, __shfl_xor(mx, off, 64));
        float e = __expf(wt - mx);
        float wn = e / wred_sum(e);
        wsh[lane] = wn;
        float pooled = 0.f;
#pragma unroll 8
        for (int pp2 = 0; pp2 < PP; ++pp2) pooled += pr_sh[pp2][lane] * wsh[pp2];
        float qv = qf[lane], rv = rf[lane];
        float s1 = wred_sum(qv * rv * p1w[lane]);
        float s2 = wred_sum((rv - qv) * pooled * p2w[lane]);
        if (lane == 0) out[b] = (s1 + p1b[0]) + 5.0f * (s2 + p2b[0]);
    }
}

extern "C" void kernel_launch(void* const* d_in, const int* in_sizes, int n_in,
                              void* d_out, int out_size, void* d_ws, size_t ws_size,
                              hipStream_t stream) {
    const int*   qry_id = (const int*)d_in[0];
    const int*   res_id = (const int*)d_in[1];
    const int*   path   = (const int*)d_in[2];
    const int*   mask   = (const int*)d_in[3];
    const float* img    = (const float*)d_in[4];
    const float* Ww     = (const float*)d_in[5];
    const float* Wb     = (const float*)d_in[6];
    const float* meta   = (const float*)d_in[7];
    const float* hw     = (const float*)d_in[8];
    const float* hb     = (const float*)d_in[9];
    const float* p1w    = (const float*)d_in[10];
    const float* p1b    = (const float*)d_in[11];
    const float* p2w    = (const float*)d_in[12];
    const float* p2b    = (const float*)d_in[13];

    float* out = (float*)d_out;

    hipLaunchKernelGGL(k_fused, dim3(BB), dim3(1024), 0, stream,
                       qry_id, res_id, path, mask, img, Ww, Wb, meta,
                       hw, hb, p1w, p1b, p2w, p2b, out);
}